// Round 1
// baseline (611.270 us; speedup 1.0000x reference)
//
#include <hip/hip_runtime.h>

#define NB 8
#define NC 64
#define NN 4096
#define NK 16
#define NO 64
#define TILE 64

// ---------------------------------------------------------------------------
// Kernel 1: per-point projections + squared norms.
// PQ[b][n][r], r in [0,192): 0..63  = x·(W1e-W2e)^T + b_edge   (P1 + bias)
//                            64..127 = x·W2e^T                  (P2)
//                            128..191= x·W2a^T                  (Q2)
// (Q1 and b_att cancel inside the softmax over k.)
// ---------------------------------------------------------------------------
__global__ __launch_bounds__(256) void proj_kernel(
    const float* __restrict__ x, const float* __restrict__ We,
    const float* __restrict__ be, const float* __restrict__ Wa,
    float* __restrict__ PQ, float* __restrict__ sq)
{
  __shared__ float xs[NC][TILE];   // [c][p]  16 KB
  __shared__ float wt[NC][192];    // [c][row] 48 KB
  const int bid = blockIdx.x;
  const int b   = bid >> 6;
  const int n0  = (bid & 63) * TILE;
  const int tid = threadIdx.x;

  const float4* xg4 = (const float4*)x;
  float4* xs4 = (float4*)xs;
  for (int i = tid; i < NC * TILE / 4; i += 256) {
    int c = i >> 4, p4 = i & 15;
    xs4[c * 16 + p4] = xg4[(b * NC + c) * (NN / 4) + (n0 >> 2) + p4];
  }
  for (int i = tid; i < 64 * NC; i += 256) {
    int o = i >> 6, c = i & 63;
    float w1 = We[o * 128 + c], w2 = We[o * 128 + 64 + c];
    wt[c][o]        = w1 - w2;
    wt[c][64 + o]   = w2;
    wt[c][128 + o]  = Wa[o * 128 + 64 + c];
  }
  __syncthreads();

  if (tid >= 192) {
    // wave 3: squared norms
    int p = tid - 192;
    float s = 0.f;
    #pragma unroll
    for (int c = 0; c < NC; ++c) { float v = xs[c][p]; s = fmaf(v, v, s); }
    sq[b * NN + n0 + p] = s;
  } else {
    const int r = tid;  // output row 0..191
    float wreg[NC];
    #pragma unroll
    for (int c = 0; c < NC; ++c) wreg[c] = wt[c][r];
    const float bias = (r < 64) ? be[r] : 0.f;
    for (int p = 0; p < TILE; p += 4) {
      float a0 = bias, a1 = bias, a2 = bias, a3 = bias;
      #pragma unroll
      for (int c = 0; c < NC; ++c) {
        float4 xv = *(const float4*)&xs[c][p];
        a0 = fmaf(wreg[c], xv.x, a0);
        a1 = fmaf(wreg[c], xv.y, a1);
        a2 = fmaf(wreg[c], xv.z, a2);
        a3 = fmaf(wreg[c], xv.w, a3);
      }
      int base = (b * NN + n0 + p) * 192 + r;
      PQ[base]           = a0;
      PQ[base + 192]     = a1;
      PQ[base + 2 * 192] = a2;
      PQ[base + 3 * 192] = a3;
    }
  }
}

// ---------------------------------------------------------------------------
// Kernel 2: fused pairwise-distance + streaming top-16 (smallest sq[m]-2*dot).
// Block: (batch, 64-row tile). Streams 64-col tiles of x.
// ---------------------------------------------------------------------------
__global__ __launch_bounds__(256) void knn_kernel(
    const float* __restrict__ x, const float* __restrict__ sq,
    int* __restrict__ nn_idx)
{
  __shared__ float rowT[NC][TILE];           // [c][p] 16 KB
  __shared__ float colT[NC][TILE];           // [c][p] 16 KB
  __shared__ float distT[TILE][TILE + 1];    // stride 65: conflict-free scan
  __shared__ float sqc[TILE];
  const int bid = blockIdx.x;
  const int b   = bid >> 6;
  const int r0  = (bid & 63) * TILE;
  const int tid = threadIdx.x;
  const float4* xg4 = (const float4*)x;

  {
    float4* rT4 = (float4*)rowT;
    for (int i = tid; i < NC * TILE / 4; i += 256) {
      int c = i >> 4, p4 = i & 15;
      rT4[c * 16 + p4] = xg4[(b * NC + c) * (NN / 4) + (r0 >> 2) + p4];
    }
  }

  // per-thread sorted top-16 (ascending); statically indexed registers only
  float bv[NK]; int bi[NK];
  #pragma unroll
  for (int t = 0; t < NK; ++t) { bv[t] = 3.0e38f; bi[t] = 0; }

  const int rr   = (tid >> 4) << 2;   // compute-phase 4 rows
  const int cc   = (tid & 15) << 2;   // compute-phase 4 cols
  const int srow = tid >> 2;          // scan-phase row
  const int ssub = tid & 3;           // scan-phase col group (16 cols)

  for (int n1 = 0; n1 < NN; n1 += TILE) {
    {
      float4* cT4 = (float4*)colT;
      for (int i = tid; i < NC * TILE / 4; i += 256) {
        int c = i >> 4, p4 = i & 15;
        cT4[c * 16 + p4] = xg4[(b * NC + c) * (NN / 4) + (n1 >> 2) + p4];
      }
      if (tid < TILE) sqc[tid] = sq[b * NN + n1 + tid];
    }
    __syncthreads();

    // 4x4 register-blocked fp32 dot tile
    float acc[4][4];
    #pragma unroll
    for (int i2 = 0; i2 < 4; ++i2)
      #pragma unroll
      for (int j = 0; j < 4; ++j) acc[i2][j] = 0.f;

    #pragma unroll 8
    for (int c = 0; c < NC; ++c) {
      const float4 av = *(const float4*)&rowT[c][rr];
      const float4 bw = *(const float4*)&colT[c][cc];
      acc[0][0]=fmaf(av.x,bw.x,acc[0][0]); acc[0][1]=fmaf(av.x,bw.y,acc[0][1]);
      acc[0][2]=fmaf(av.x,bw.z,acc[0][2]); acc[0][3]=fmaf(av.x,bw.w,acc[0][3]);
      acc[1][0]=fmaf(av.y,bw.x,acc[1][0]); acc[1][1]=fmaf(av.y,bw.y,acc[1][1]);
      acc[1][2]=fmaf(av.y,bw.z,acc[1][2]); acc[1][3]=fmaf(av.y,bw.w,acc[1][3]);
      acc[2][0]=fmaf(av.z,bw.x,acc[2][0]); acc[2][1]=fmaf(av.z,bw.y,acc[2][1]);
      acc[2][2]=fmaf(av.z,bw.z,acc[2][2]); acc[2][3]=fmaf(av.z,bw.w,acc[2][3]);
      acc[3][0]=fmaf(av.w,bw.x,acc[3][0]); acc[3][1]=fmaf(av.w,bw.y,acc[3][1]);
      acc[3][2]=fmaf(av.w,bw.z,acc[3][2]); acc[3][3]=fmaf(av.w,bw.w,acc[3][3]);
    }
    #pragma unroll
    for (int i2 = 0; i2 < 4; ++i2)
      #pragma unroll
      for (int j = 0; j < 4; ++j)
        distT[rr + i2][cc + j] = fmaf(-2.f, acc[i2][j], sqc[cc + j]);
    __syncthreads();

    // streaming top-k update: each thread scans 16 cols of its row
    for (int i2 = 0; i2 < 16; ++i2) {
      float v = distT[srow][ssub * 16 + i2];
      if (v < bv[NK - 1]) {
        bv[NK - 1] = v; bi[NK - 1] = n1 + ssub * 16 + i2;
        #pragma unroll
        for (int q = NK - 1; q > 0; --q) {
          if (bv[q] < bv[q - 1]) {
            float tv = bv[q]; bv[q] = bv[q - 1]; bv[q - 1] = tv;
            int   ti = bi[q]; bi[q] = bi[q - 1]; bi[q - 1] = ti;
          }
        }
      }
    }
  }

  // merge the 4 per-row lists (reuse rowT/colT as scratch)
  float* mv = &rowT[0][0];
  int*   mi = (int*)&colT[0][0];
  #pragma unroll
  for (int t = 0; t < NK; ++t) {
    mv[(srow * 4 + ssub) * NK + t] = bv[t];
    mi[(srow * 4 + ssub) * NK + t] = bi[t];
  }
  __syncthreads();
  if (ssub == 0) {
    for (int s2 = 1; s2 < 4; ++s2) {
      for (int t = 0; t < NK; ++t) {
        float v = mv[(srow * 4 + s2) * NK + t];
        if (v >= bv[NK - 1]) break;           // lists are sorted ascending
        bv[NK - 1] = v; bi[NK - 1] = mi[(srow * 4 + s2) * NK + t];
        #pragma unroll
        for (int q = NK - 1; q > 0; --q) {
          if (bv[q] < bv[q - 1]) {
            float tv = bv[q]; bv[q] = bv[q - 1]; bv[q - 1] = tv;
            int   ti = bi[q]; bi[q] = bi[q - 1]; bi[q - 1] = ti;
          }
        }
      }
    }
    #pragma unroll
    for (int t = 0; t < NK; ++t)
      nn_idx[(b * NN + r0 + srow) * NK + t] = bi[t];
  }
}

// ---------------------------------------------------------------------------
// Kernel 3: gather neighbors' P2/Q2, softmax over k, weighted sum, write
// (B,O,N) via LDS transpose for coalesced stores.
// ---------------------------------------------------------------------------
__global__ __launch_bounds__(256) void out_kernel(
    const float* __restrict__ PQ, const int* __restrict__ nn_idx,
    float* __restrict__ out)
{
  __shared__ float ot[TILE][TILE + 1];
  const int bid = blockIdx.x;
  const int b   = bid >> 6;
  const int n0  = (bid & 63) * TILE;
  const int tid = threadIdx.x;
  const int w = tid >> 6, o = tid & 63;   // wave w handles 16 points, lane = o

  for (int pi = 0; pi < 16; ++pi) {
    const int p = w * 16 + pi;
    const int n = n0 + p;
    const float* pqn = PQ + (b * NN + n) * 192;
    const float p1b  = pqn[o];
    const int* idxp  = nn_idx + (b * NN + n) * NK;
    float p2[NK], q2[NK];
    #pragma unroll
    for (int t = 0; t < NK; ++t) {
      int j = idxp[t];                       // broadcast load across lanes
      const float* pqj = PQ + (b * NN + j) * 192;
      p2[t] = pqj[64 + o];                   // coalesced 256B per k
      q2[t] = pqj[128 + o];
    }
    float m = q2[0];
    #pragma unroll
    for (int t = 1; t < NK; ++t) m = fmaxf(m, q2[t]);
    float s = 0.f, num = 0.f;
    #pragma unroll
    for (int t = 0; t < NK; ++t) {
      float e = __expf(q2[t] - m);
      s += e;
      num = fmaf(e, p1b + p2[t], num);
    }
    ot[p][o] = num / s;
  }
  __syncthreads();

  const int oo = tid >> 2, qq = tid & 3;
  float* og = out + (b * NO + oo) * NN + n0 + qq * 16;
  #pragma unroll
  for (int i = 0; i < 4; ++i) {
    float4 v;
    v.x = ot[qq * 16 + i * 4 + 0][oo];
    v.y = ot[qq * 16 + i * 4 + 1][oo];
    v.z = ot[qq * 16 + i * 4 + 2][oo];
    v.w = ot[qq * 16 + i * 4 + 3][oo];
    *(float4*)&og[i * 4] = v;
  }
}

// ---------------------------------------------------------------------------
extern "C" void kernel_launch(void* const* d_in, const int* in_sizes, int n_in,
                              void* d_out, int out_size, void* d_ws, size_t ws_size,
                              hipStream_t stream)
{
  const float* x  = (const float*)d_in[0];
  const float* We = (const float*)d_in[1];
  const float* be = (const float*)d_in[2];
  const float* Wa = (const float*)d_in[3];
  // d_in[4] = b_att (cancels in softmax), d_in[5] = k (hardcoded 16)
  float* out = (float*)d_out;

  char* ws = (char*)d_ws;
  float* sq = (float*)ws;                                  // 128 KB
  float* PQ = (float*)(ws + (1 << 17));                    // 24 MB
  int*   nn = (int*)(ws + (1 << 17) + (size_t)NB * NN * 192 * 4);  // 2 MB

  dim3 blk(256);
  dim3 grd(NB * (NN / TILE));   // 512 blocks
  proj_kernel<<<grd, blk, 0, stream>>>(x, We, be, Wa, PQ, sq);
  knn_kernel<<<grd, blk, 0, stream>>>(x, sq, nn);
  out_kernel<<<grd, blk, 0, stream>>>(PQ, nn, out);
}

// Round 2
// 562.527 us; speedup vs baseline: 1.0867x; 1.0867x over previous
//
#include <hip/hip_runtime.h>

#define NB 8
#define NC 64
#define NN 4096
#define NK 16
#define NO 64
#define TILE 64
#define NCHUNK 2
#define CHCOLS (NN / NCHUNK)   // 2048 cols per chunk

// monotone map: fp32 -> uint such that float order == unsigned int order
__device__ __forceinline__ unsigned fmap(float x) {
  unsigned u = __float_as_uint(x);
  return (u & 0x80000000u) ? ~u : (u | 0x80000000u);
}
__device__ __forceinline__ float funmap(unsigned m) {
  unsigned u = (m & 0x80000000u) ? (m ^ 0x80000000u) : ~m;
  return __uint_as_float(u);
}

// ---------------------------------------------------------------------------
// Kernel 1: per-point projections + squared norms.
// PQ[b][n][r], r in [0,192): 0..63  = x·(W1e-W2e)^T + b_edge   (P1 + bias)
//                            64..127 = x·W2e^T                  (P2)
//                            128..191= x·W2a^T                  (Q2)
// (Q1 and b_att cancel inside the softmax over k.)
// ---------------------------------------------------------------------------
__global__ __launch_bounds__(256) void proj_kernel(
    const float* __restrict__ x, const float* __restrict__ We,
    const float* __restrict__ be, const float* __restrict__ Wa,
    float* __restrict__ PQ, float* __restrict__ sq)
{
  __shared__ float xs[NC][TILE];
  __shared__ float wt[NC][192];
  const int bid = blockIdx.x;
  const int b   = bid >> 6;
  const int n0  = (bid & 63) * TILE;
  const int tid = threadIdx.x;

  const float4* xg4 = (const float4*)x;
  float4* xs4 = (float4*)xs;
  for (int i = tid; i < NC * TILE / 4; i += 256) {
    int c = i >> 4, p4 = i & 15;
    xs4[c * 16 + p4] = xg4[(b * NC + c) * (NN / 4) + (n0 >> 2) + p4];
  }
  for (int i = tid; i < 64 * NC; i += 256) {
    int o = i >> 6, c = i & 63;
    float w1 = We[o * 128 + c], w2 = We[o * 128 + 64 + c];
    wt[c][o]        = w1 - w2;
    wt[c][64 + o]   = w2;
    wt[c][128 + o]  = Wa[o * 128 + 64 + c];
  }
  __syncthreads();

  if (tid >= 192) {
    int p = tid - 192;
    float s = 0.f;
    #pragma unroll
    for (int c = 0; c < NC; ++c) { float v = xs[c][p]; s = fmaf(v, v, s); }
    sq[b * NN + n0 + p] = s;
  } else {
    const int r = tid;
    float wreg[NC];
    #pragma unroll
    for (int c = 0; c < NC; ++c) wreg[c] = wt[c][r];
    const float bias = (r < 64) ? be[r] : 0.f;
    for (int p = 0; p < TILE; p += 4) {
      float a0 = bias, a1 = bias, a2 = bias, a3 = bias;
      #pragma unroll
      for (int c = 0; c < NC; ++c) {
        float4 xv = *(const float4*)&xs[c][p];
        a0 = fmaf(wreg[c], xv.x, a0);
        a1 = fmaf(wreg[c], xv.y, a1);
        a2 = fmaf(wreg[c], xv.z, a2);
        a3 = fmaf(wreg[c], xv.w, a3);
      }
      int base = (b * NN + n0 + p) * 192 + r;
      PQ[base]           = a0;
      PQ[base + 192]     = a1;
      PQ[base + 2 * 192] = a2;
      PQ[base + 3 * 192] = a3;
    }
  }
}

// ---------------------------------------------------------------------------
// Kernel 2: fused pairwise-distance + streaming top-16 over a 2048-col chunk.
// Per-row shared threshold (LDS atomicMin) + extract-min rounds to keep the
// expensive insertion body rare at wave level.
// ---------------------------------------------------------------------------
__global__ __launch_bounds__(256) void knn_kernel(
    const float* __restrict__ x, const float* __restrict__ sq,
    float* __restrict__ partV, unsigned short* __restrict__ partI)
{
  __shared__ float rowT[NC][TILE];        // 16 KB
  __shared__ float colT[NC][TILE];        // 16 KB
  __shared__ float distT[TILE][68];       // 17 KB, stride 68 -> b128-aligned rows
  __shared__ float sqc[TILE];
  __shared__ unsigned thrU[TILE];
  const int bid = blockIdx.x;
  const int b   = bid >> 7;
  const int rt  = (bid >> 1) & 63;
  const int ch  = bid & 1;
  const int r0  = rt * TILE;
  const int c0  = ch * CHCOLS;
  const int tid = threadIdx.x;
  const float4* xg4 = (const float4*)x;

  {
    float4* rT4 = (float4*)rowT;
    for (int i = tid; i < NC * TILE / 4; i += 256) {
      int c = i >> 4, p4 = i & 15;
      rT4[c * 16 + p4] = xg4[(b * NC + c) * (NN / 4) + (r0 >> 2) + p4];
    }
    if (tid < TILE) thrU[tid] = 0xFFFFFFFFu;
  }

  float bv[NK]; int bi[NK];
  #pragma unroll
  for (int t = 0; t < NK; ++t) { bv[t] = 3.0e38f; bi[t] = 0; }

  const int rr   = (tid >> 4) << 2;
  const int cc   = (tid & 15) << 2;
  const int srow = tid >> 2;
  const int ssub = tid & 3;

  for (int n1 = c0; n1 < c0 + CHCOLS; n1 += TILE) {
    {
      float4* cT4 = (float4*)colT;
      for (int i = tid; i < NC * TILE / 4; i += 256) {
        int c = i >> 4, p4 = i & 15;
        cT4[c * 16 + p4] = xg4[(b * NC + c) * (NN / 4) + (n1 >> 2) + p4];
      }
      if (tid < TILE) sqc[tid] = sq[b * NN + n1 + tid];
    }
    __syncthreads();

    float acc[4][4];
    #pragma unroll
    for (int i2 = 0; i2 < 4; ++i2)
      #pragma unroll
      for (int j = 0; j < 4; ++j) acc[i2][j] = 0.f;

    #pragma unroll 8
    for (int c = 0; c < NC; ++c) {
      const float4 av = *(const float4*)&rowT[c][rr];
      const float4 bw = *(const float4*)&colT[c][cc];
      acc[0][0]=fmaf(av.x,bw.x,acc[0][0]); acc[0][1]=fmaf(av.x,bw.y,acc[0][1]);
      acc[0][2]=fmaf(av.x,bw.z,acc[0][2]); acc[0][3]=fmaf(av.x,bw.w,acc[0][3]);
      acc[1][0]=fmaf(av.y,bw.x,acc[1][0]); acc[1][1]=fmaf(av.y,bw.y,acc[1][1]);
      acc[1][2]=fmaf(av.y,bw.z,acc[1][2]); acc[1][3]=fmaf(av.y,bw.w,acc[1][3]);
      acc[2][0]=fmaf(av.z,bw.x,acc[2][0]); acc[2][1]=fmaf(av.z,bw.y,acc[2][1]);
      acc[2][2]=fmaf(av.z,bw.z,acc[2][2]); acc[2][3]=fmaf(av.z,bw.w,acc[2][3]);
      acc[3][0]=fmaf(av.w,bw.x,acc[3][0]); acc[3][1]=fmaf(av.w,bw.y,acc[3][1]);
      acc[3][2]=fmaf(av.w,bw.z,acc[3][2]); acc[3][3]=fmaf(av.w,bw.w,acc[3][3]);
    }
    #pragma unroll
    for (int i2 = 0; i2 < 4; ++i2) {
      float4 w;
      w.x = fmaf(-2.f, acc[i2][0], sqc[cc + 0]);
      w.y = fmaf(-2.f, acc[i2][1], sqc[cc + 1]);
      w.z = fmaf(-2.f, acc[i2][2], sqc[cc + 2]);
      w.w = fmaf(-2.f, acc[i2][3], sqc[cc + 3]);
      *(float4*)&distT[rr + i2][cc] = w;
    }
    __syncthreads();

    // ---- scan: 16 dists in regs, min-with-index tree, rare extract rounds ----
    const float thrF = funmap(thrU[srow]);
    float d[16];
    #pragma unroll
    for (int j4 = 0; j4 < 4; ++j4) {
      float4 t4 = *(const float4*)&distT[srow][ssub * 16 + j4 * 4];
      d[j4 * 4 + 0] = t4.x; d[j4 * 4 + 1] = t4.y;
      d[j4 * 4 + 2] = t4.z; d[j4 * 4 + 3] = t4.w;
    }
    float m = d[0]; int mi = 0;
    #pragma unroll
    for (int i = 1; i < 16; ++i) {
      bool c = d[i] < m; m = c ? d[i] : m; mi = c ? i : mi;
    }
    float guard = fminf(bv[NK - 1], thrF);
    for (int rnd = 0; rnd < NK; ++rnd) {
      bool ins = m < guard;
      if (!__any(ins)) break;
      float v  = ins ? m : 3.0e38f;
      int  vmi = ins ? mi : -1;
      if (v < bv[NK - 1]) {
        bv[NK - 1] = v; bi[NK - 1] = n1 + ssub * 16 + vmi;
        #pragma unroll
        for (int q = NK - 1; q > 0; --q) {
          if (bv[q] < bv[q - 1]) {
            float tv = bv[q]; bv[q] = bv[q - 1]; bv[q - 1] = tv;
            int   ti = bi[q]; bi[q] = bi[q - 1]; bi[q - 1] = ti;
          }
        }
      }
      #pragma unroll
      for (int i = 0; i < 16; ++i) d[i] = (i == vmi) ? 3.0e38f : d[i];
      m = d[0]; mi = 0;
      #pragma unroll
      for (int i = 1; i < 16; ++i) {
        bool c = d[i] < m; m = c ? d[i] : m; mi = c ? i : mi;
      }
      guard = fminf(bv[NK - 1], thrF);
    }
    atomicMin(&thrU[srow], fmap(bv[NK - 1]));
  }

  // merge the 4 per-row lists (reuse rowT/colT as scratch)
  float* mv  = &rowT[0][0];
  int*   mi2 = (int*)&colT[0][0];
  #pragma unroll
  for (int t = 0; t < NK; ++t) {
    mv [(srow * 4 + ssub) * NK + t] = bv[t];
    mi2[(srow * 4 + ssub) * NK + t] = bi[t];
  }
  __syncthreads();
  if (ssub == 0) {
    for (int s2 = 1; s2 < 4; ++s2) {
      for (int t = 0; t < NK; ++t) {
        float v = mv[(srow * 4 + s2) * NK + t];
        if (v >= bv[NK - 1]) break;
        bv[NK - 1] = v; bi[NK - 1] = mi2[(srow * 4 + s2) * NK + t];
        #pragma unroll
        for (int q = NK - 1; q > 0; --q) {
          if (bv[q] < bv[q - 1]) {
            float tv = bv[q]; bv[q] = bv[q - 1]; bv[q - 1] = tv;
            int   ti = bi[q]; bi[q] = bi[q - 1]; bi[q - 1] = ti;
          }
        }
      }
    }
    const int L = (b * NCHUNK + ch) * NN + r0 + srow;
    #pragma unroll
    for (int t = 0; t < NK; ++t) {
      partV[L * NK + t] = bv[t];
      partI[L * NK + t] = (unsigned short)bi[t];
    }
  }
}

// ---------------------------------------------------------------------------
// Kernel 2b: merge the two chunk top-16 lists per row (both sorted ascending).
// ---------------------------------------------------------------------------
__global__ __launch_bounds__(256) void merge_kernel(
    const float* __restrict__ partV, const unsigned short* __restrict__ partI,
    int* __restrict__ nn_idx)
{
  const int row = blockIdx.x * 256 + threadIdx.x;   // b*NN + n
  if (row >= NB * NN) return;
  const int b = row >> 12, n = row & (NN - 1);
  const int LA = (b * NCHUNK + 0) * NN + n;
  const int LB = (b * NCHUNK + 1) * NN + n;

  float bv[NK]; int bi[NK];
  #pragma unroll
  for (int t = 0; t < NK; ++t) {
    bv[t] = partV[LA * NK + t];
    bi[t] = (int)partI[LA * NK + t];
  }
  for (int t = 0; t < NK; ++t) {
    float v = partV[LB * NK + t];
    if (v >= bv[NK - 1]) break;   // sorted ascending; strict keeps chunk0 first on ties
    bv[NK - 1] = v; bi[NK - 1] = (int)partI[LB * NK + t];
    #pragma unroll
    for (int q = NK - 1; q > 0; --q) {
      if (bv[q] < bv[q - 1]) {
        float tv = bv[q]; bv[q] = bv[q - 1]; bv[q - 1] = tv;
        int   ti = bi[q]; bi[q] = bi[q - 1]; bi[q - 1] = ti;
      }
    }
  }
  #pragma unroll
  for (int t = 0; t < NK; ++t) nn_idx[row * NK + t] = bi[t];
}

// ---------------------------------------------------------------------------
// Kernel 3: gather neighbors' P2/Q2, softmax over k, weighted sum, write
// (B,O,N) via LDS transpose for coalesced stores.
// ---------------------------------------------------------------------------
__global__ __launch_bounds__(256) void out_kernel(
    const float* __restrict__ PQ, const int* __restrict__ nn_idx,
    float* __restrict__ out)
{
  __shared__ float ot[TILE][TILE + 1];
  const int bid = blockIdx.x;
  const int b   = bid >> 6;
  const int n0  = (bid & 63) * TILE;
  const int tid = threadIdx.x;
  const int w = tid >> 6, o = tid & 63;

  for (int pi = 0; pi < 16; ++pi) {
    const int p = w * 16 + pi;
    const int n = n0 + p;
    const float* pqn = PQ + (b * NN + n) * 192;
    const float p1b  = pqn[o];
    const int* idxp  = nn_idx + (b * NN + n) * NK;
    float p2[NK], q2[NK];
    #pragma unroll
    for (int t = 0; t < NK; ++t) {
      int j = idxp[t];
      const float* pqj = PQ + (b * NN + j) * 192;
      p2[t] = pqj[64 + o];
      q2[t] = pqj[128 + o];
    }
    float m = q2[0];
    #pragma unroll
    for (int t = 1; t < NK; ++t) m = fmaxf(m, q2[t]);
    float s = 0.f, num = 0.f;
    #pragma unroll
    for (int t = 0; t < NK; ++t) {
      float e = __expf(q2[t] - m);
      s += e;
      num = fmaf(e, p1b + p2[t], num);
    }
    ot[p][o] = num / s;
  }
  __syncthreads();

  const int oo = tid >> 2, qq = tid & 3;
  float* og = out + (b * NO + oo) * NN + n0 + qq * 16;
  #pragma unroll
  for (int i = 0; i < 4; ++i) {
    float4 v;
    v.x = ot[qq * 16 + i * 4 + 0][oo];
    v.y = ot[qq * 16 + i * 4 + 1][oo];
    v.z = ot[qq * 16 + i * 4 + 2][oo];
    v.w = ot[qq * 16 + i * 4 + 3][oo];
    *(float4*)&og[i * 4] = v;
  }
}

// ---------------------------------------------------------------------------
extern "C" void kernel_launch(void* const* d_in, const int* in_sizes, int n_in,
                              void* d_out, int out_size, void* d_ws, size_t ws_size,
                              hipStream_t stream)
{
  const float* x  = (const float*)d_in[0];
  const float* We = (const float*)d_in[1];
  const float* be = (const float*)d_in[2];
  const float* Wa = (const float*)d_in[3];
  float* out = (float*)d_out;

  char* ws = (char*)d_ws;
  size_t off = 0;
  float* sq = (float*)(ws + off);  off += (size_t)NB * NN * 4;                 // 128 KB
  float* PQ = (float*)(ws + off);  off += (size_t)NB * NN * 192 * 4;           // 24 MB
  int*   nn = (int*)(ws + off);    off += (size_t)NB * NN * NK * 4;            // 2 MB
  float* pV = (float*)(ws + off);  off += (size_t)NB * NCHUNK * NN * NK * 4;   // 4 MB
  unsigned short* pI = (unsigned short*)(ws + off);                            // 2 MB

  dim3 blk(256);
  proj_kernel<<<dim3(NB * (NN / TILE)), blk, 0, stream>>>(x, We, be, Wa, PQ, sq);
  knn_kernel<<<dim3(NB * (NN / TILE) * NCHUNK), blk, 0, stream>>>(x, sq, pV, pI);
  merge_kernel<<<dim3(NB * NN / 256), blk, 0, stream>>>(pV, pI, nn);
  out_kernel<<<dim3(NB * (NN / TILE)), blk, 0, stream>>>(PQ, nn, out);
}